// Round 6
// baseline (257.563 us; speedup 1.0000x reference)
//
#include <hip/hip_runtime.h>

// ---------------------------------------------------------------------------
// BCNet: v_=relu(v@Wv^T+bv); q_=relu(q@Wq^T+bq); out[b,h,v,q]=sum_k h[h,k]*v_*q_ + hbias[h]
// Round 6: round-5 m97 structure (verified: 0 bank conflicts, 772 TF) +
//  - chunked XCD remap (contiguous logical ranges per XCD -> A-panel L2 locality)
//  - __launch_bounds__(256,4): 4 blocks/CU (more cross-block drain overlap;
//    bilinear's 1024 blocks become exactly all-resident)
// ---------------------------------------------------------------------------

typedef _Float16 h8 __attribute__((ext_vector_type(8)));
typedef float f32x4 __attribute__((ext_vector_type(4)));

#define B_   32
#define NV_  512
#define NQ_  128
#define VD_  2048
#define QD_  1024
#define HK_  1536
#define HO_  8

__device__ __forceinline__ void gload_lds16(const void* g, void* l) {
  __builtin_amdgcn_global_load_lds(
      (const __attribute__((address_space(1))) void*)g,
      (__attribute__((address_space(3))) void*)l, 16, 0, 0);
}

// ---------------------------------------------------------------------------
// Fused f32 -> f16 conversion for all 5 inputs, 8 elems/thread, one launch.
// Unit boundaries (8-elem units): v 4194304 | q 524288 | Wv 393216 |
// Wq 196608 | h 1536 => total 5309952 = 20742 * 256.
// ---------------------------------------------------------------------------
__global__ __launch_bounds__(256) void cvt_all(
    const float* __restrict__ v, const float* __restrict__ q,
    const float* __restrict__ Wv, const float* __restrict__ Wq,
    const float* __restrict__ hm,
    _Float16* __restrict__ v16, _Float16* __restrict__ q16,
    _Float16* __restrict__ Wv16, _Float16* __restrict__ Wq16,
    _Float16* __restrict__ h16) {
  int i = blockIdx.x * blockDim.x + threadIdx.x;
  const float* src;
  _Float16* dst;
  if (i < 4194304)      { src = v;  dst = v16; }
  else if (i < 4718592) { src = q;  dst = q16;  i -= 4194304; }
  else if (i < 5111808) { src = Wv; dst = Wv16; i -= 4718592; }
  else if (i < 5308416) { src = Wq; dst = Wq16; i -= 5111808; }
  else                  { src = hm; dst = h16;  i -= 5308416; }
  const float4* p = (const float4*)src;
  float4 a = p[i * 2], b = p[i * 2 + 1];
  h8 o;
  o[0] = (_Float16)a.x; o[1] = (_Float16)a.y; o[2] = (_Float16)a.z; o[3] = (_Float16)a.w;
  o[4] = (_Float16)b.x; o[5] = (_Float16)b.y; o[6] = (_Float16)b.z; o[7] = (_Float16)b.w;
  ((h8*)dst)[i] = o;
}

// ---------------------------------------------------------------------------
// GEMM: out = relu(A @ Bw^T + bias), f16 in/out. A: MxK, Bw: NxK (K-major).
// 128x128 tile, BK=64 as two [128][32] kk-slabs, 4 waves (2x2), 64x64/wave.
// LDS 32 KB, swizzle slot^=(row>>1)&3 (verified conflict-free).
// Chunked XCD remap: hw j -> logical (j&7)*(nwg/8)+(j>>3); logical order is
// bcol-fastest, so each XCD sweeps a contiguous disjoint brow range.
// Grid: (N/128, M/128), product divisible by 8.
// ---------------------------------------------------------------------------
template <int KTOT>
__global__ __launch_bounds__(256, 4) void gemm_m97_relu_f16(
    const _Float16* __restrict__ A, const _Float16* __restrict__ Bw,
    const float* __restrict__ bias, _Float16* __restrict__ out, int N) {
  __shared__ __align__(16) _Float16 As[2][128 * 32];
  __shared__ __align__(16) _Float16 Bs[2][128 * 32];

  const int t = threadIdx.x;
  const int lane = t & 63;
  const int wave = t >> 6;
  const int wm = wave >> 1, wn = wave & 1;

  const int nwg = gridDim.x * gridDim.y;
  const int j = blockIdx.y * gridDim.x + blockIdx.x;
  const int l = (j & 7) * (nwg >> 3) + (j >> 3);
  const int bcol = (l % gridDim.x) * 128;
  const int brow = (l / gridDim.x) * 128;

  // staging: thread t -> row t>>2 (0..63), 16B slot t&3; LDS dest linear,
  // global source column pre-swizzled by the involution slot^=(row>>1)&3.
  const int scol = ((t & 3) ^ ((t >> 3) & 3)) * 8;
  const _Float16* Ab = A + (size_t)(brow + (t >> 2)) * KTOT + scol;
  const _Float16* Bb = Bw + (size_t)(bcol + (t >> 2)) * KTOT + scol;

  f32x4 acc[4][4] = {};

  for (int kt = 0; kt < KTOT / 64; ++kt) {
    __syncthreads();  // previous tile's readers done
#pragma unroll
    for (int kk = 0; kk < 2; ++kk) {
      gload_lds16(Ab + kt * 64 + kk * 32, &As[kk][t * 8]);
      gload_lds16(Ab + (size_t)64 * KTOT + kt * 64 + kk * 32, &As[kk][2048 + t * 8]);
      gload_lds16(Bb + kt * 64 + kk * 32, &Bs[kk][t * 8]);
      gload_lds16(Bb + (size_t)64 * KTOT + kt * 64 + kk * 32, &Bs[kk][2048 + t * 8]);
    }
    asm volatile("s_waitcnt vmcnt(0)" ::: "memory");
    __syncthreads();
#pragma unroll
    for (int kk = 0; kk < 2; ++kk) {
      h8 af[4], bf[4];
#pragma unroll
      for (int m = 0; m < 4; ++m) {
        const int row = wm * 64 + m * 16 + (lane & 15);
        af[m] = *(const h8*)&As[kk][row * 32 + ((lane >> 4) ^ ((row >> 1) & 3)) * 8];
      }
#pragma unroll
      for (int n = 0; n < 4; ++n) {
        const int row = wn * 64 + n * 16 + (lane & 15);
        bf[n] = *(const h8*)&Bs[kk][row * 32 + ((lane >> 4) ^ ((row >> 1) & 3)) * 8];
      }
#pragma unroll
      for (int m = 0; m < 4; ++m)
#pragma unroll
        for (int n = 0; n < 4; ++n)
          acc[m][n] = __builtin_amdgcn_mfma_f32_16x16x32_f16(af[m], bf[n], acc[m][n], 0, 0, 0);
    }
  }

#pragma unroll
  for (int m = 0; m < 4; ++m)
#pragma unroll
    for (int n = 0; n < 4; ++n) {
      const int col = bcol + wn * 64 + n * 16 + (lane & 15);
      const float bb = bias[col];
#pragma unroll
      for (int r = 0; r < 4; ++r) {
        const int row = brow + wm * 64 + m * 16 + (lane >> 4) * 4 + r;
        float val = acc[m][n][r] + bb;
        out[(size_t)row * N + col] = (_Float16)(val > 0.f ? val : 0.f);
      }
    }
}

// ---------------------------------------------------------------------------
// Bilinear: out[b,h,v,q] = sum_k vh[b,v,k]*(h16[h,k]*qh[b,q,k]) + hbias[h]
// m97 structure. A (vh) via gload_lds; B = qh*h reg-staged, swizzled ds_write;
// h row cached in LDS. Grid (4, 256) = 1024 blocks = exactly 4/CU.
// Chunked remap puts each b's 32 blocks (4 mt x 8 h) on one XCD.
// ---------------------------------------------------------------------------
__global__ __launch_bounds__(256, 4) void bilinear_m97_f16(
    const _Float16* __restrict__ vh, const _Float16* __restrict__ qh,
    const _Float16* __restrict__ h16, const float* __restrict__ hbias,
    float* __restrict__ out) {
  __shared__ __align__(16) _Float16 As[2][128 * 32];
  __shared__ __align__(16) _Float16 Bs[2][128 * 32];
  __shared__ __align__(16) _Float16 hl[HK_];

  const int t = threadIdx.x;
  const int lane = t & 63;
  const int wave = t >> 6;
  const int wm = wave >> 1, wn = wave & 1;

  const int j = blockIdx.y * gridDim.x + blockIdx.x;  // nwg = 1024
  const int l = (j & 7) * 128 + (j >> 3);
  const int mt = l & 3;        // 0..3
  const int bh = l >> 2;       // 0..255
  const int b = bh >> 3, h = bh & 7;

  const int scol = ((t & 3) ^ ((t >> 3) & 3)) * 8;
  const _Float16* Ab = vh + ((size_t)b * NV_ + mt * 128 + (t >> 2)) * HK_ + scol;
  const _Float16* Qb = qh + (size_t)b * NQ_ * HK_;

  // cache the h row (3 KB); consumed after the loop-top __syncthreads()
  for (int i = t; i < HK_ / 8; i += 256)
    *(h8*)&hl[i * 8] = *(const h8*)&h16[(size_t)h * HK_ + i * 8];

  const int qrow = t >> 2;  // 0..63
  const int qs = t & 3;

  f32x4 acc[4][4] = {};

  for (int kt = 0; kt < HK_ / 64; ++kt) {
    __syncthreads();
#pragma unroll
    for (int kk = 0; kk < 2; ++kk) {
      gload_lds16(Ab + kt * 64 + kk * 32, &As[kk][t * 8]);
      gload_lds16(Ab + (size_t)64 * HK_ + kt * 64 + kk * 32, &As[kk][2048 + t * 8]);
    }
#pragma unroll
    for (int u = 0; u < 2; ++u) {
      const int row = u * 64 + qrow;
#pragma unroll
      for (int kk = 0; kk < 2; ++kk) {
        const int col = kt * 64 + kk * 32 + qs * 8;
        h8 qv = *(const h8*)&Qb[(size_t)row * HK_ + col];
        h8 hv = *(const h8*)&hl[col];
        *(h8*)&Bs[kk][row * 32 + (qs ^ ((row >> 1) & 3)) * 8] = qv * hv;
      }
    }
    asm volatile("s_waitcnt vmcnt(0)" ::: "memory");
    __syncthreads();
#pragma unroll
    for (int kk = 0; kk < 2; ++kk) {
      h8 af[4], bf[4];
#pragma unroll
      for (int m = 0; m < 4; ++m) {
        const int row = wm * 64 + m * 16 + (lane & 15);
        af[m] = *(const h8*)&As[kk][row * 32 + ((lane >> 4) ^ ((row >> 1) & 3)) * 8];
      }
#pragma unroll
      for (int n = 0; n < 4; ++n) {
        const int row = wn * 64 + n * 16 + (lane & 15);
        bf[n] = *(const h8*)&Bs[kk][row * 32 + ((lane >> 4) ^ ((row >> 1) & 3)) * 8];
      }
#pragma unroll
      for (int m = 0; m < 4; ++m)
#pragma unroll
        for (int n = 0; n < 4; ++n)
          acc[m][n] = __builtin_amdgcn_mfma_f32_16x16x32_f16(af[m], bf[n], acc[m][n], 0, 0, 0);
    }
  }

  const float bb = hbias[h];
  float* O = out + ((size_t)bh * NV_ + (size_t)mt * 128) * NQ_;
#pragma unroll
  for (int m = 0; m < 4; ++m)
#pragma unroll
    for (int n = 0; n < 4; ++n)
#pragma unroll
      for (int r = 0; r < 4; ++r) {
        const int row = wm * 64 + m * 16 + (lane >> 4) * 4 + r;
        const int col = wn * 64 + n * 16 + (lane & 15);
        O[(size_t)row * NQ_ + col] = acc[m][n][r] + bb;
      }
}

// ---------------------------------------------------------------------------
// Workspace layout (bytes): v16@0 (67,108,864) q16@67108864 (8,388,608)
// Wv16@75497472 (6,291,456) Wq16@81788928 (3,145,728) vh@84934656 (50,331,648)
// qh@135266304 (12,582,912) h16@147849216 (24,576) total 147,873,792
// ---------------------------------------------------------------------------
extern "C" void kernel_launch(void* const* d_in, const int* in_sizes, int n_in,
                              void* d_out, int out_size, void* d_ws,
                              size_t ws_size, hipStream_t stream) {
  const float* v = (const float*)d_in[0];
  const float* q = (const float*)d_in[1];
  const float* Wv = (const float*)d_in[2];
  const float* bv = (const float*)d_in[3];
  const float* Wq = (const float*)d_in[4];
  const float* bq = (const float*)d_in[5];
  const float* hmat = (const float*)d_in[6];
  const float* hbias = (const float*)d_in[7];

  if (ws_size < 147873792u) return;

  char* ws = (char*)d_ws;
  _Float16* v16 = (_Float16*)(ws);
  _Float16* q16 = (_Float16*)(ws + 67108864);
  _Float16* Wv16 = (_Float16*)(ws + 75497472);
  _Float16* Wq16 = (_Float16*)(ws + 81788928);
  _Float16* vh = (_Float16*)(ws + 84934656);
  _Float16* qh = (_Float16*)(ws + 135266304);
  _Float16* h16 = (_Float16*)(ws + 147849216);

  cvt_all<<<dim3(20742), 256, 0, stream>>>(v, q, Wv, Wq, hmat,
                                           v16, q16, Wv16, Wq16, h16);

  // v_ = relu(v @ Wv^T + bv): grid (12,128) = 1536 blocks (192/XCD chunk)
  gemm_m97_relu_f16<VD_><<<dim3(HK_ / 128, 16384 / 128), 256, 0, stream>>>(
      v16, Wv16, bv, vh, HK_);
  // q_ = relu(q @ Wq^T + bq): grid (12,32) = 384 blocks (48/XCD chunk)
  gemm_m97_relu_f16<QD_><<<dim3(HK_ / 128, 4096 / 128), 256, 0, stream>>>(
      q16, Wq16, bq, qh, HK_);

  // logits: grid (4,256) = 1024 blocks = exactly 4/CU, b-grouped per XCD
  bilinear_m97_f16<<<dim3(NV_ / 128, B_ * HO_), 256, 0, stream>>>(
      vh, qh, h16, hbias, (float*)d_out);
}